// Round 9
// baseline (307.240 us; speedup 1.0000x reference)
//
#include <hip/hip_runtime.h>

#define NQ   4096
#define NKV  32768
#define C    256
#define KNN  100
#define QB   4        // queries per block (2 waves per query, 8 waves/block)
#define NB   2048     // cutoff buckets: f32 d2 bits >> 20 (1/8 binade)
#define NSUB 4096     // subsample = first NSUB original-order keys (i.i.d.)
#define RSUB 48       // subsample rank for cutoff (global expected ~500)
#define CAP  1024     // u32 candidate capacity per query
#define RCAP 128      // refine capacity (expected ~105)
#define RSPLIT 52     // primary wave rows [0,52), secondary [52,100)
#define NCELL 32768   // 32^3 key cells
#define GRIDC 32
#define HCELL 0.25f
#define INVH  4.0f

// ws layout (bytes)
#define WS_KPKS   0                 // float4[NKV] (kx,ky,kz,as_float(origId)) cell-sorted, 512K
#define WS_CSTART (512*1024)        // int[NCELL+1]  (ends ~644K)
#define WS_CCNT   (648*1024)        // int[NCELL]    count->cursor
#define WS_BINCNT (776*1024)        // int[512]      (contiguous after CCNT: one memset)
#define WS_BINOF  (780*1024)        // int[NQ]
#define WS_BINOFF (796*1024)        // int[512]
#define WS_SORTED (800*1024)        // int[NQ]

__device__ __forceinline__ int cellOf(float x, float y, float z) {
    int ix = min(GRIDC - 1, max(0, (int)floorf((x + 4.0f) * INVH)));
    int iy = min(GRIDC - 1, max(0, (int)floorf((y + 4.0f) * INVH)));
    int iz = min(GRIDC - 1, max(0, (int)floorf((z + 4.0f) * INVH)));
    return (iz * GRIDC + iy) * GRIDC + ix;
}

// Scan key: fma-contracted f32 d2. Only needs error far below the +2-bucket
// (1/8-binade) margin; exact ranking is f64 on the <=128 survivors.
__device__ __forceinline__ unsigned int scankey(float sq_, float qx, float qy, float qz,
                                                float kx, float ky, float kz, float sk) {
    float dot = __builtin_fmaf(kx, qx, __builtin_fmaf(ky, qy, __fmul_rn(kz, qz)));
    float d2  = __builtin_fmaf(-2.0f, dot, __fadd_rn(sq_, sk));
    return __float_as_uint(fmaxf(d2, 0.0f));   // monotone; bucket = bits>>20 <= 2039
}

// ---- pre-kernel 1: count keys per cell; count queries per spatial bin ----
extern "C" __global__ void count_all(const float* __restrict__ k_pos,
                                     const float* __restrict__ q_pos,
                                     int* __restrict__ cellCnt,
                                     int* __restrict__ binOf, int* __restrict__ binCnt) {
    int j = blockIdx.x * 256 + threadIdx.x;
    if (j < NKV) {
        atomicAdd(&cellCnt[cellOf(k_pos[3*j], k_pos[3*j+1], k_pos[3*j+2])], 1);
    }
    if (j < NQ) {
        int ix = min(7, max(0, (int)floorf(q_pos[3 * j + 0] + 4.0f)));
        int iy = min(7, max(0, (int)floorf(q_pos[3 * j + 1] + 4.0f)));
        int iz = min(7, max(0, (int)floorf(q_pos[3 * j + 2] + 4.0f)));
        int b = ix | (iy << 3) | (iz << 6);
        binOf[j] = b;
        atomicAdd(&binCnt[b], 1);
    }
}

// ---- pre-kernel 2: prefix over 32768 cells (1024 thr x 32) + 512 query bins ----
extern "C" __global__ void cell_prefix(const int* __restrict__ cellCnt,
                                       int* __restrict__ cellStart, int* __restrict__ cellCur,
                                       const int* __restrict__ binCnt, int* __restrict__ binOff) {
    __shared__ int part[1024];
    __shared__ int qtmp[512];
    int t = threadIdx.x;
    int base = t * 32;
    int local[32];
    int s = 0;
    #pragma unroll
    for (int i = 0; i < 32; i++) { local[i] = cellCnt[base + i]; s += local[i]; }
    part[t] = s;
    __syncthreads();
    for (int off = 1; off < 1024; off <<= 1) {
        int v = (t >= off) ? part[t - off] : 0;
        __syncthreads();
        part[t] += v;
        __syncthreads();
    }
    int run = part[t] - s;                 // exclusive base
    #pragma unroll
    for (int i = 0; i < 32; i++) {
        cellStart[base + i] = run;
        cellCur[base + i]  = run;
        run += local[i];
    }
    if (t == 1023) cellStart[NCELL] = run; // == NKV
    // query 512-bin exclusive prefix
    __syncthreads();
    if (t < 512) qtmp[t] = binCnt[t];
    __syncthreads();
    for (int off = 1; off < 512; off <<= 1) {
        int v = 0;
        if (t < 512 && t >= off) v = qtmp[t - off];
        __syncthreads();
        if (t < 512) qtmp[t] += v;
        __syncthreads();
    }
    if (t < 512) binOff[t] = qtmp[t] - binCnt[t];
}

// ---- pre-kernel 3: scatter keys cell-sorted; scatter queries bin-sorted ----
extern "C" __global__ void scatter_all(const float* __restrict__ k_pos,
                                       int* __restrict__ cellCur, float4* __restrict__ kpkS,
                                       const int* __restrict__ binOf, int* __restrict__ binOff,
                                       int* __restrict__ sortedIdx) {
    int j = blockIdx.x * 256 + threadIdx.x;
    if (j < NKV) {
        float kx = k_pos[3*j], ky = k_pos[3*j+1], kz = k_pos[3*j+2];
        int pos = atomicAdd(&cellCur[cellOf(kx, ky, kz)], 1);
        kpkS[pos] = make_float4(kx, ky, kz, __int_as_float(j));   // origId in .w
    }
    if (j < NQ) {
        int pos = atomicAdd(&binOff[binOf[j]], 1);
        sortedIdx[pos] = j;
    }
}

extern "C" __global__ __launch_bounds__(512, 8)
void sparse_attn_fused(const float* __restrict__ q_feat,
                       const float* __restrict__ k_feat,
                       const float* __restrict__ v_feat,
                       const float* __restrict__ q_pos,
                       const float* __restrict__ k_pos,
                       const float4* __restrict__ kpkS,
                       const int* __restrict__ cellStart,
                       const int* __restrict__ sortedIdx,
                       const float* __restrict__ gamma,
                       const float* __restrict__ beta,
                       float* __restrict__ out) {
    // 16 KB pool: u16-packed histograms (2 pairs x 2048 buckets), then u32 cand
    __shared__ __align__(16) unsigned int pool[QB * CAP];
    unsigned int* hist = pool;
    unsigned int* cand = pool;
    __shared__ __align__(16) unsigned long long refine[QB * RCAP];  // 4 KB
    __shared__ float  sArr[QB * 128];                               // 2 KB raw scores
    __shared__ float4 accbuf[QB * 64];                              // 4 KB PV partials
    __shared__ unsigned int sUpper[QB];
    __shared__ int sCnt[QB], sCnt2[QB];

    const int tid  = threadIdx.x;
    const int lane = tid & 63;
    const int w    = tid >> 6;     // 0..7
    const int qw   = w & 3;        // query slot
    const int role = w >> 2;       // 0 = primary, 1 = secondary
    // XCD-aware swizzle: XCD x gets a contiguous spatially-sorted query range.
    const int grp = (blockIdx.x & 7) * (gridDim.x >> 3) + (blockIdx.x >> 3);
    const int qbase = grp * QB;

    // ---- query positions (spatially-sorted indirection) ----
    int   qi[QB];
    float qx[QB], qy[QB], qz[QB], sq[QB];
    #pragma unroll
    for (int q = 0; q < QB; q++) {
        qi[q] = sortedIdx[qbase + q];
        qx[q] = q_pos[3 * qi[q] + 0];
        qy[q] = q_pos[3 * qi[q] + 1];
        qz[q] = q_pos[3 * qi[q] + 2];
        sq[q] = __builtin_fmaf(qx[q], qx[q],
                __builtin_fmaf(qy[q], qy[q], __fmul_rn(qz[q], qz[q])));
    }

    // ---- phase 1: subsample histogram over first NSUB original keys ----
    for (int b = tid; b < QB * CAP; b += 512) pool[b] = 0;
    if (tid < QB) { sCnt[tid] = 0; sCnt2[tid] = 0; }
    __syncthreads();

    for (int j = tid; j < NSUB; j += 512) {
        float kx = k_pos[3*j], ky = k_pos[3*j+1], kz = k_pos[3*j+2];
        float skv = __builtin_fmaf(kx, kx, __builtin_fmaf(ky, ky, __fmul_rn(kz, kz)));
        #pragma unroll
        for (int q = 0; q < QB; q++) {
            unsigned int key = scankey(sq[q], qx[q], qy[q], qz[q], kx, ky, kz, skv);
            atomicAdd(&hist[(q >> 1) * NB + (key >> 20)], 1u << ((q & 1) * 16));
        }
    }
    __syncthreads();

    // ---- phase 2: cutoff at subsample rank RSUB (+2 margin), primary waves ----
    if (role == 0) {
        const int p = qw >> 1, sh = (qw & 1) * 16;
        const int bb = lane * (NB / 64);
        int s = 0;
        #pragma unroll
        for (int b = 0; b < NB / 64; b++) s += (hist[p * NB + bb + b] >> sh) & 0xffff;
        int pre = s;
        #pragma unroll
        for (int off = 1; off < 64; off <<= 1) {
            int t = __shfl_up(pre, off);
            if (lane >= off) pre += t;
        }
        unsigned long long m = __ballot(pre >= RSUB);
        int fl = (int)__builtin_ctzll(m);
        int excl = __shfl(pre - s, fl);
        if (lane == fl) {
            int cum = excl, b = bb;
            while (cum + (int)((hist[p * NB + b] >> sh) & 0xffff) < RSUB) {
                cum += (hist[p * NB + b] >> sh) & 0xffff;
                b++;
            }
            unsigned int ub = min((unsigned int)b + 2u, 2040u);
            sUpper[qw] = ub << 20;   // ub==2040 -> 0x7F800000 (+inf): full-grid fallback
        }
    }
    __syncthreads();
    unsigned int up[QB];
    #pragma unroll
    for (int q = 0; q < QB; q++) up[q] = sUpper[q];
    __syncthreads();   // hist reads done before cand overlays pool

    // ---- phase 3: cell-range collect (wave pair per query, rows split) ----
    {
        const float upf = __uint_as_float(up[qw]);
        const float R = __fsqrt_rn(upf);
        int ix0 = min(GRIDC-1, max(0, (int)floorf((qx[qw] - R + 4.0f) * INVH)));
        int ix1 = min(GRIDC-1, max(0, (int)floorf((qx[qw] + R + 4.0f) * INVH)));
        int iy0 = min(GRIDC-1, max(0, (int)floorf((qy[qw] - R + 4.0f) * INVH)));
        int iy1 = min(GRIDC-1, max(0, (int)floorf((qy[qw] + R + 4.0f) * INVH)));
        int iz0 = min(GRIDC-1, max(0, (int)floorf((qz[qw] - R + 4.0f) * INVH)));
        int iz1 = min(GRIDC-1, max(0, (int)floorf((qz[qw] + R + 4.0f) * INVH)));
        int r = 0;
        for (int iz = iz0; iz <= iz1; iz++) {
            float zlo = (iz == 0)       ? -1e30f : (-4.0f + iz * HCELL);        // edge cells
            float zhi = (iz == GRIDC-1) ?  1e30f : (-4.0f + (iz + 1) * HCELL);  // hold outliers
            float dz = fmaxf(fmaxf(zlo - qz[qw], qz[qw] - zhi), 0.0f);
            float dz2 = dz * dz;
            for (int iy = iy0; iy <= iy1; iy++, r++) {
                if ((r & 1) != role) continue;              // split rows across wave pair
                float ylo = (iy == 0)       ? -1e30f : (-4.0f + iy * HCELL);
                float yhi = (iy == GRIDC-1) ?  1e30f : (-4.0f + (iy + 1) * HCELL);
                float dy = fmaxf(fmaxf(ylo - qy[qw], qy[qw] - yhi), 0.0f);
                if (__builtin_fmaf(dy, dy, dz2) > upf) continue;   // row min-dist prune
                int cb = (iz * GRIDC + iy) * GRIDC;
                int kbeg = cellStart[cb + ix0];
                int kend = cellStart[cb + ix1 + 1];         // contiguous run in x
                for (int kk = kbeg + lane; kk < kend; kk += 64) {
                    float4 kp = kpkS[kk];
                    float skv = __builtin_fmaf(kp.x, kp.x,
                                __builtin_fmaf(kp.y, kp.y, __fmul_rn(kp.z, kp.z)));
                    unsigned int key = scankey(sq[qw], qx[qw], qy[qw], qz[qw],
                                               kp.x, kp.y, kp.z, skv);
                    if (key < up[qw]) {
                        int pos = atomicAdd(&sCnt[qw], 1);
                        if (pos < CAP)
                            cand[qw * CAP + pos] =
                                (key & 0xFFFF8000u) | (unsigned int)__float_as_int(kp.w);
                    }
                }
            }
        }
    }
    __syncthreads();

    // ---- phases 4-5 (primary waves): ballot binary-search + f64 refine ----
    if (role == 0) {
        unsigned int kreg[CAP / 64];
        const int cnt = min(sCnt[qw], CAP);
        #pragma unroll
        for (int k = 0; k < CAP / 64; k++) {
            int i = lane + k * 64;
            kreg[k] = (i < cnt) ? cand[qw * CAP + i] : 0xFFFFFFFFu;
        }
        unsigned int lo = 0, hi = 0x1FFFFu;
        while (lo < hi) {                      // wave-uniform (reduced count)
            unsigned int mid = (lo + hi) >> 1;
            int c = 0;
            #pragma unroll
            for (int k = 0; k < CAP / 64; k++) c += ((kreg[k] >> 15) <= mid) ? 1 : 0;
            #pragma unroll
            for (int off = 32; off > 0; off >>= 1) c += __shfl_xor(c, off);
            if (c >= KNN) hi = mid; else lo = mid + 1;
        }
        const unsigned int tstar = lo;         // minimal trunc-key with count >= 100

        #pragma unroll
        for (int k = 0; k < CAP / 64; k++) {
            if ((kreg[k] >> 15) <= tstar) {    // padding (0x1FFFF) never passes
                int idx = (int)(kreg[k] & 0x7fffu);    // ORIGINAL key index
                float kx = k_pos[3*idx], ky = k_pos[3*idx+1], kz = k_pos[3*idx+2];
                double dqx = (double)qx[qw], dqy = (double)qy[qw], dqz = (double)qz[qw];
                double dkx = (double)kx, dky = (double)ky, dkz = (double)kz;
                double sq64 = dqx * dqx + dqy * dqy + dqz * dqz;
                double sk64 = dkx * dkx + dky * dky + dkz * dkz;
                double dot64 = dqx * dkx + dqy * dky + dqz * dkz;
                double d2 = sq64 + sk64 - 2.0 * dot64;
                if (d2 < 0.0) d2 = 0.0;
                unsigned long long kb = (unsigned long long)__double_as_longlong(d2);
                int pos = atomicAdd(&sCnt2[qw], 1);
                if (pos < RCAP)
                    refine[qw * RCAP + pos] = (kb & ~0x7fffULL) | (unsigned long long)idx;
            }
        }
    }
    __syncthreads();

    // ---- phase 6: register bitonic sort of 128 u64, DUPLICATED in both waves ----
    unsigned long long v0, v1;
    {
        const int cnt2 = min(sCnt2[qw], RCAP);
        v0 = (lane < cnt2)      ? refine[qw * RCAP + lane]      : ~0ULL;
        v1 = (64 + lane < cnt2) ? refine[qw * RCAP + 64 + lane] : ~0ULL;
    }
    #pragma unroll
    for (int k = 2; k <= 128; k <<= 1) {
        #pragma unroll
        for (int j = 64; j > 0; j >>= 1) {
            if (j > (k >> 1)) continue;
            if (j == 64) {  // cross-reg, same lane (only k=128); asc always
                unsigned long long mn = v0 < v1 ? v0 : v1;
                unsigned long long mx = v0 < v1 ? v1 : v0;
                v0 = mn; v1 = mx;
            } else {
                unsigned long long o0 = __shfl_xor(v0, j);
                unsigned long long o1 = __shfl_xor(v1, j);
                bool lower = (lane & j) == 0;
                bool asc0 = ((lane & k) == 0);          // element e0 = lane
                bool asc1 = (((64 + lane) & k) == 0);   // element e1 = 64+lane
                v0 = ((v0 < o0) == (lower == asc0)) ? v0 : o0;
                v1 = ((v1 < o1) == (lower == asc1)) ? v1 : o1;
            }
        }
    }
    const int id0r = (int)(v0 & 0x7fffULL);
    const int id1r = (int)(v1 & 0x7fffULL);

    // ---- phase 7: attention scores, row-split between the wave pair ----
    const int qn = qi[qw];
    const float4 qv = ((const float4*)(q_feat + (size_t)qn * C))[lane];
    {
        const int ibeg = role ? RSPLIT : 0;
        const int iend = role ? KNN : RSPLIT;
        for (int i = ibeg; i < iend; i += 4) {
            const int rsel = i >> 6, base = i & 63;
            const int idsrc = rsel ? id1r : id0r;
            int id0 = __shfl(idsrc, base + 0);
            int id1 = __shfl(idsrc, base + 1);
            int id2 = __shfl(idsrc, base + 2);
            int id3 = __shfl(idsrc, base + 3);
            float4 k0 = ((const float4*)(k_feat + (size_t)id0 * C))[lane];
            float4 k1 = ((const float4*)(k_feat + (size_t)id1 * C))[lane];
            float4 k2 = ((const float4*)(k_feat + (size_t)id2 * C))[lane];
            float4 k3 = ((const float4*)(k_feat + (size_t)id3 * C))[lane];
            float d0 = qv.x*k0.x + qv.y*k0.y + qv.z*k0.z + qv.w*k0.w;
            float d1 = qv.x*k1.x + qv.y*k1.y + qv.z*k1.z + qv.w*k1.w;
            float d2 = qv.x*k2.x + qv.y*k2.y + qv.z*k2.z + qv.w*k2.w;
            float d3 = qv.x*k3.x + qv.y*k3.y + qv.z*k3.z + qv.w*k3.w;
            #pragma unroll
            for (int off = 32; off > 0; off >>= 1) {
                d0 += __shfl_xor(d0, off);
                d1 += __shfl_xor(d1, off);
                d2 += __shfl_xor(d2, off);
                d3 += __shfl_xor(d3, off);
            }
            if (lane == 0) {
                sArr[qw * 128 + i + 0] = d0 * 0.0625f;
                sArr[qw * 128 + i + 1] = d1 * 0.0625f;
                sArr[qw * 128 + i + 2] = d2 * 0.0625f;
                sArr[qw * 128 + i + 3] = d3 * 0.0625f;
            }
        }
    }
    __syncthreads();

    // ---- phase 8: softmax over 100, DUPLICATED (deterministic) ----
    float invS, e0v, e1v;
    {
        float a = sArr[qw * 128 + lane];                       // rows 0-63
        bool hasB = (lane + 64 < KNN);
        float b = hasB ? sArr[qw * 128 + 64 + lane] : -3.0e38f;
        float mx = fmaxf(a, b);
        #pragma unroll
        for (int off = 32; off > 0; off >>= 1) mx = fmaxf(mx, __shfl_xor(mx, off));
        e0v = expf(a - mx);
        e1v = hasB ? expf(b - mx) : 0.0f;
        float s = e0v + e1v;
        #pragma unroll
        for (int off = 32; off > 0; off >>= 1) s += __shfl_xor(s, off);
        invS = 1.0f / s;
    }

    // ---- phase 9: PV gather, row-split ----
    float4 acc = make_float4(0.f, 0.f, 0.f, 0.f);
    {
        const int ibeg = role ? RSPLIT : 0;
        const int iend = role ? KNN : RSPLIT;
        for (int i = ibeg; i < iend; i += 4) {
            const int rsel = i >> 6, base = i & 63;
            const int idsrc = rsel ? id1r : id0r;
            const float esrc = rsel ? e1v : e0v;
            int id0 = __shfl(idsrc, base + 0);
            int id1 = __shfl(idsrc, base + 1);
            int id2 = __shfl(idsrc, base + 2);
            int id3 = __shfl(idsrc, base + 3);
            float w0 = __shfl(esrc, base + 0);
            float w1 = __shfl(esrc, base + 1);
            float w2 = __shfl(esrc, base + 2);
            float w3 = __shfl(esrc, base + 3);
            float4 p0 = ((const float4*)(v_feat + (size_t)id0 * C))[lane];
            float4 p1 = ((const float4*)(v_feat + (size_t)id1 * C))[lane];
            float4 p2 = ((const float4*)(v_feat + (size_t)id2 * C))[lane];
            float4 p3 = ((const float4*)(v_feat + (size_t)id3 * C))[lane];
            acc.x = fmaf(w0, p0.x, acc.x); acc.y = fmaf(w0, p0.y, acc.y);
            acc.z = fmaf(w0, p0.z, acc.z); acc.w = fmaf(w0, p0.w, acc.w);
            acc.x = fmaf(w1, p1.x, acc.x); acc.y = fmaf(w1, p1.y, acc.y);
            acc.z = fmaf(w1, p1.z, acc.z); acc.w = fmaf(w1, p1.w, acc.w);
            acc.x = fmaf(w2, p2.x, acc.x); acc.y = fmaf(w2, p2.y, acc.y);
            acc.z = fmaf(w2, p2.z, acc.z); acc.w = fmaf(w2, p2.w, acc.w);
            acc.x = fmaf(w3, p3.x, acc.x); acc.y = fmaf(w3, p3.y, acc.y);
            acc.z = fmaf(w3, p3.z, acc.z); acc.w = fmaf(w3, p3.w, acc.w);
        }
    }
    if (role == 1) accbuf[qw * 64 + lane] = acc;
    __syncthreads();

    // ---- phase 10: combine partials, LayerNorm, store (primary wave) ----
    if (role == 0) {
        float4 part = accbuf[qw * 64 + lane];
        acc.x += part.x; acc.y += part.y; acc.z += part.z; acc.w += part.w;
        // y = 2x (res_feat fully overwritten by the scatter -> res + x = 2x)
        float4 y;
        y.x = 2.0f * acc.x * invS; y.y = 2.0f * acc.y * invS;
        y.z = 2.0f * acc.z * invS; y.w = 2.0f * acc.w * invS;

        float t1 = y.x + y.y + y.z + y.w;
        float t2 = y.x*y.x + y.y*y.y + y.z*y.z + y.w*y.w;
        #pragma unroll
        for (int off = 32; off > 0; off >>= 1) {
            t1 += __shfl_xor(t1, off);
            t2 += __shfl_xor(t2, off);
        }
        float mean = t1 * (1.0f / C);
        float var  = fmaxf(t2 * (1.0f / C) - mean * mean, 0.0f);
        float rstd = 1.0f / sqrtf(var + 1e-5f);

        const float4 g4 = ((const float4*)gamma)[lane];
        const float4 b4 = ((const float4*)beta)[lane];
        float4 o;
        o.x = (y.x - mean) * rstd * g4.x + b4.x;
        o.y = (y.y - mean) * rstd * g4.y + b4.y;
        o.z = (y.z - mean) * rstd * g4.z + b4.z;
        o.w = (y.w - mean) * rstd * g4.w + b4.w;
        ((float4*)(out + (size_t)qn * C))[lane] = o;
    }
}

extern "C" void kernel_launch(void* const* d_in, const int* in_sizes, int n_in,
                              void* d_out, int out_size, void* d_ws, size_t ws_size,
                              hipStream_t stream) {
    // setup_inputs order: res_feat, q_feat, k_feat, v_feat, q_pos, k_pos, gamma, beta
    // res_feat (d_in[0]) is dead: scatter overwrites all rows, y = 2x.
    const float* q_feat = (const float*)d_in[1];
    const float* k_feat = (const float*)d_in[2];
    const float* v_feat = (const float*)d_in[3];
    const float* q_pos  = (const float*)d_in[4];
    const float* k_pos  = (const float*)d_in[5];
    const float* gamma  = (const float*)d_in[6];
    const float* beta   = (const float*)d_in[7];
    float* out = (float*)d_out;

    char* ws = (char*)d_ws;
    float4* kpkS    = (float4*)(ws + WS_KPKS);
    int* cellStart  = (int*)(ws + WS_CSTART);
    int* cellCur    = (int*)(ws + WS_CCNT);
    int* binCnt     = (int*)(ws + WS_BINCNT);
    int* binOf      = (int*)(ws + WS_BINOF);
    int* binOff     = (int*)(ws + WS_BINOFF);
    int* sortedIdx  = (int*)(ws + WS_SORTED);

    // zero cellCnt + binCnt in one contiguous memset
    hipMemsetAsync(cellCur, 0, (NCELL + 512) * sizeof(int), stream);
    count_all  <<<NKV / 256, 256, 0, stream>>>(k_pos, q_pos, cellCur, binOf, binCnt);
    cell_prefix<<<1, 1024, 0, stream>>>(cellCur, cellStart, cellCur, binCnt, binOff);
    scatter_all<<<NKV / 256, 256, 0, stream>>>(k_pos, cellCur, kpkS,
                                               binOf, binOff, sortedIdx);
    sparse_attn_fused<<<NQ / QB, 512, 0, stream>>>(q_feat, k_feat, v_feat,
                                                   q_pos, k_pos, kpkS, cellStart,
                                                   sortedIdx, gamma, beta, out);
}

// Round 11
// 228.099 us; speedup vs baseline: 1.3470x; 1.3470x over previous
//
#include <hip/hip_runtime.h>

#define NQ   4096
#define NKV  32768
#define C    256
#define KNN  100
#define QB   4        // queries per block (2 waves per query, 8 waves/block)
#define NB   2048     // cutoff buckets: f32 d2 bits >> 20 (1/8 binade)
#define NSUB 4096     // subsample = first NSUB original-order keys (i.i.d.)
#define RSUB 48       // subsample rank for cutoff (global expected ~500)
#define CAP  1024     // u32 candidate capacity per query
#define RCAP 128      // refine capacity (expected ~105)
#define RSPLIT 52     // primary wave rows [0,52), secondary [52,100)
#define NCELL 4096    // 16^3 key cells
#define GRIDC 16
#define HCELL 0.5f
#define INVH  2.0f

// ws layout (bytes)
#define WS_KPKS   0                 // float4[NKV] (kx,ky,kz,as_float(origId)) cell-sorted, 512K
#define WS_CSTART (512*1024)        // int[NCELL+1]
#define WS_CCNT   (532*1024)        // int[NCELL] count->cursor
#define WS_BINCNT (548*1024)        // int[512]  (contiguous after CCNT: one memset)
#define WS_BINOF  (552*1024)        // int[NQ]
#define WS_BINOFF (568*1024)        // int[512]
#define WS_SORTED (572*1024)        // int[NQ]

__device__ __forceinline__ int cellOf(float x, float y, float z) {
    int ix = min(GRIDC - 1, max(0, (int)floorf((x + 4.0f) * INVH)));
    int iy = min(GRIDC - 1, max(0, (int)floorf((y + 4.0f) * INVH)));
    int iz = min(GRIDC - 1, max(0, (int)floorf((z + 4.0f) * INVH)));
    return (iz * GRIDC + iy) * GRIDC + ix;
}

// Scan key: fma-contracted f32 d2. Only needs error far below the +2-bucket
// (1/8-binade) margin; exact ranking is f64 on the <=128 survivors.
__device__ __forceinline__ unsigned int scankey(float sq_, float qx, float qy, float qz,
                                                float kx, float ky, float kz, float sk) {
    float dot = __builtin_fmaf(kx, qx, __builtin_fmaf(ky, qy, __fmul_rn(kz, qz)));
    float d2  = __builtin_fmaf(-2.0f, dot, __fadd_rn(sq_, sk));
    return __float_as_uint(fmaxf(d2, 0.0f));   // monotone; bucket = bits>>20 <= 2039
}

// ---- pre-kernel 1: count keys per cell; count queries per spatial bin ----
extern "C" __global__ void count_all(const float* __restrict__ k_pos,
                                     const float* __restrict__ q_pos,
                                     int* __restrict__ cellCnt,
                                     int* __restrict__ binOf, int* __restrict__ binCnt) {
    int j = blockIdx.x * 256 + threadIdx.x;
    if (j < NKV) {
        atomicAdd(&cellCnt[cellOf(k_pos[3*j], k_pos[3*j+1], k_pos[3*j+2])], 1);
    }
    if (j < NQ) {
        int ix = min(7, max(0, (int)floorf(q_pos[3 * j + 0] + 4.0f)));
        int iy = min(7, max(0, (int)floorf(q_pos[3 * j + 1] + 4.0f)));
        int iz = min(7, max(0, (int)floorf(q_pos[3 * j + 2] + 4.0f)));
        int b = ix | (iy << 3) | (iz << 6);
        binOf[j] = b;
        atomicAdd(&binCnt[b], 1);
    }
}

// ---- pre-kernel 2: prefix over 4096 cells (1024 thr x 4) + 512 query bins ----
extern "C" __global__ void cell_prefix(const int* __restrict__ cellCnt,
                                       int* __restrict__ cellStart, int* __restrict__ cellCur,
                                       const int* __restrict__ binCnt, int* __restrict__ binOff) {
    __shared__ int part[1024];
    __shared__ int qtmp[512];
    int t = threadIdx.x;
    int base = t * 4;
    int local[4];
    int s = 0;
    #pragma unroll
    for (int i = 0; i < 4; i++) { local[i] = cellCnt[base + i]; s += local[i]; }
    part[t] = s;
    __syncthreads();
    for (int off = 1; off < 1024; off <<= 1) {
        int v = (t >= off) ? part[t - off] : 0;
        __syncthreads();
        part[t] += v;
        __syncthreads();
    }
    int run = part[t] - s;                 // exclusive base
    #pragma unroll
    for (int i = 0; i < 4; i++) {
        cellStart[base + i] = run;
        cellCur[base + i]  = run;
        run += local[i];
    }
    if (t == 1023) cellStart[NCELL] = run; // == NKV
    __syncthreads();
    if (t < 512) qtmp[t] = binCnt[t];
    __syncthreads();
    for (int off = 1; off < 512; off <<= 1) {
        int v = 0;
        if (t < 512 && t >= off) v = qtmp[t - off];
        __syncthreads();
        if (t < 512) qtmp[t] += v;
        __syncthreads();
    }
    if (t < 512) binOff[t] = qtmp[t] - binCnt[t];
}

// ---- pre-kernel 3: scatter keys cell-sorted; scatter queries bin-sorted ----
extern "C" __global__ void scatter_all(const float* __restrict__ k_pos,
                                       int* __restrict__ cellCur, float4* __restrict__ kpkS,
                                       const int* __restrict__ binOf, int* __restrict__ binOff,
                                       int* __restrict__ sortedIdx) {
    int j = blockIdx.x * 256 + threadIdx.x;
    if (j < NKV) {
        float kx = k_pos[3*j], ky = k_pos[3*j+1], kz = k_pos[3*j+2];
        int pos = atomicAdd(&cellCur[cellOf(kx, ky, kz)], 1);
        kpkS[pos] = make_float4(kx, ky, kz, __int_as_float(j));   // origId in .w
    }
    if (j < NQ) {
        int pos = atomicAdd(&binOff[binOf[j]], 1);
        sortedIdx[pos] = j;
    }
}

extern "C" __global__ __launch_bounds__(512, 8)
void sparse_attn_fused(const float* __restrict__ q_feat,
                       const float* __restrict__ k_feat,
                       const float* __restrict__ v_feat,
                       const float* __restrict__ q_pos,
                       const float* __restrict__ k_pos,
                       const float4* __restrict__ kpkS,
                       const int* __restrict__ cellStart,
                       const int* __restrict__ sortedIdx,
                       const float* __restrict__ gamma,
                       const float* __restrict__ beta,
                       float* __restrict__ out) {
    // 16 KB pool: u16-packed histograms (2 pairs x 2048 buckets), then u32 cand
    __shared__ __align__(16) unsigned int pool[QB * CAP];
    unsigned int* hist = pool;
    unsigned int* cand = pool;
    __shared__ __align__(16) unsigned long long refine[QB * RCAP];  // 4 KB
    __shared__ float  sArr[QB * 128];                               // 2 KB raw scores
    __shared__ float4 accbuf[QB * 64];                              // 4 KB PV partials
    __shared__ unsigned int sUpper[QB];
    __shared__ int sCnt[QB], sCnt2[QB];

    const int tid  = threadIdx.x;
    const int lane = tid & 63;
    const int w    = tid >> 6;     // 0..7
    const int qw   = w & 3;        // query slot
    const int role = w >> 2;       // 0 = primary, 1 = secondary
    // XCD-aware swizzle: XCD x gets a contiguous spatially-sorted query range.
    const int grp = (blockIdx.x & 7) * (gridDim.x >> 3) + (blockIdx.x >> 3);
    const int qbase = grp * QB;

    // ---- query positions (spatially-sorted indirection) ----
    int   qi[QB];
    float qx[QB], qy[QB], qz[QB], sq[QB];
    #pragma unroll
    for (int q = 0; q < QB; q++) {
        qi[q] = sortedIdx[qbase + q];
        qx[q] = q_pos[3 * qi[q] + 0];
        qy[q] = q_pos[3 * qi[q] + 1];
        qz[q] = q_pos[3 * qi[q] + 2];
        sq[q] = __builtin_fmaf(qx[q], qx[q],
                __builtin_fmaf(qy[q], qy[q], __fmul_rn(qz[q], qz[q])));
    }

    // ---- phase 1: subsample histogram over first NSUB original keys ----
    for (int b = tid; b < QB * CAP; b += 512) pool[b] = 0;
    if (tid < QB) { sCnt[tid] = 0; sCnt2[tid] = 0; }
    __syncthreads();

    for (int j = tid; j < NSUB; j += 512) {
        float kx = k_pos[3*j], ky = k_pos[3*j+1], kz = k_pos[3*j+2];
        float skv = __builtin_fmaf(kx, kx, __builtin_fmaf(ky, ky, __fmul_rn(kz, kz)));
        #pragma unroll
        for (int q = 0; q < QB; q++) {
            unsigned int key = scankey(sq[q], qx[q], qy[q], qz[q], kx, ky, kz, skv);
            atomicAdd(&hist[(q >> 1) * NB + (key >> 20)], 1u << ((q & 1) * 16));
        }
    }
    __syncthreads();

    // ---- phase 2: cutoff at subsample rank RSUB (+2 margin), primary waves ----
    if (role == 0) {
        const int p = qw >> 1, sh = (qw & 1) * 16;
        const int bb = lane * (NB / 64);
        int s = 0;
        #pragma unroll
        for (int b = 0; b < NB / 64; b++) s += (hist[p * NB + bb + b] >> sh) & 0xffff;
        int pre = s;
        #pragma unroll
        for (int off = 1; off < 64; off <<= 1) {
            int t = __shfl_up(pre, off);
            if (lane >= off) pre += t;
        }
        unsigned long long m = __ballot(pre >= RSUB);
        int fl = (int)__builtin_ctzll(m);
        int excl = __shfl(pre - s, fl);
        if (lane == fl) {
            int cum = excl, b = bb;
            while (cum + (int)((hist[p * NB + b] >> sh) & 0xffff) < RSUB) {
                cum += (hist[p * NB + b] >> sh) & 0xffff;
                b++;
            }
            unsigned int ub = min((unsigned int)b + 2u, 2040u);
            sUpper[qw] = ub << 20;   // ub==2040 -> +inf: full-grid fallback
        }
    }
    __syncthreads();
    unsigned int up[QB];
    #pragma unroll
    for (int q = 0; q < QB; q++) up[q] = sUpper[q];
    __syncthreads();   // hist reads done before cand overlays pool

    // ---- phase 3: cell-range collect, R9-verified serial row loop at grid 16
    //      (rows parity-split across the wave pair; per-row x-tightening) ----
    {
        const float upf = __uint_as_float(up[qw]);
        const float R = __fsqrt_rn(upf);
        const float qxv = qx[qw], qyv = qy[qw], qzv = qz[qw];
        int iy0 = min(GRIDC-1, max(0, (int)floorf((qyv - R + 4.0f) * INVH)));
        int iy1 = min(GRIDC-1, max(0, (int)floorf((qyv + R + 4.0f) * INVH)));
        int iz0 = min(GRIDC-1, max(0, (int)floorf((qzv - R + 4.0f) * INVH)));
        int iz1 = min(GRIDC-1, max(0, (int)floorf((qzv + R + 4.0f) * INVH)));
        int r = 0;
        for (int iz = iz0; iz <= iz1; iz++) {
            float zlo = (iz == 0)       ? -1e30f : (-4.0f + iz * HCELL);       // edge cells
            float zhi = (iz == GRIDC-1) ?  1e30f : (-4.0f + (iz + 1) * HCELL); // hold outliers
            float dz = fmaxf(fmaxf(zlo - qzv, qzv - zhi), 0.0f);
            float dz2 = dz * dz;
            for (int iy = iy0; iy <= iy1; iy++, r++) {
                if ((r & 1) != role) continue;              // split rows across wave pair
                float ylo = (iy == 0)       ? -1e30f : (-4.0f + iy * HCELL);
                float yhi = (iy == GRIDC-1) ?  1e30f : (-4.0f + (iy + 1) * HCELL);
                float dy = fmaxf(fmaxf(ylo - qyv, qyv - yhi), 0.0f);
                float dyz2 = __builtin_fmaf(dy, dy, dz2);
                if (dyz2 > upf) continue;                   // row min-dist prune
                float xr = __fsqrt_rn(fmaxf(upf - dyz2, 0.0f));   // ball x-tighten
                int jx0 = min(GRIDC-1, max(0, (int)floorf((qxv - xr + 4.0f) * INVH)));
                int jx1 = min(GRIDC-1, max(0, (int)floorf((qxv + xr + 4.0f) * INVH)));
                int cb = (iz * GRIDC + iy) * GRIDC;
                int kbeg = cellStart[cb + jx0];
                int kend = cellStart[cb + jx1 + 1];         // contiguous run in x
                for (int kk = kbeg + lane; kk < kend; kk += 64) {
                    float4 kp = kpkS[kk];
                    float skv = __builtin_fmaf(kp.x, kp.x,
                                __builtin_fmaf(kp.y, kp.y, __fmul_rn(kp.z, kp.z)));
                    unsigned int key = scankey(sq[qw], qxv, qyv, qzv,
                                               kp.x, kp.y, kp.z, skv);
                    if (key < up[qw]) {
                        int pos = atomicAdd(&sCnt[qw], 1);
                        if (pos < CAP)
                            cand[qw * CAP + pos] =
                                (key & 0xFFFF8000u) | (unsigned int)__float_as_int(kp.w);
                    }
                }
            }
        }
    }
    __syncthreads();

    // ---- phases 4-5 (primary waves): ballot binary-search + f64 refine ----
    if (role == 0) {
        unsigned int kreg[CAP / 64];
        const int cnt = min(sCnt[qw], CAP);
        #pragma unroll
        for (int k = 0; k < CAP / 64; k++) {
            int i = lane + k * 64;
            kreg[k] = (i < cnt) ? cand[qw * CAP + i] : 0xFFFFFFFFu;
        }
        unsigned int lo = 0, hi = 0x1FFFFu;
        while (lo < hi) {                      // wave-uniform (reduced count)
            unsigned int mid = (lo + hi) >> 1;
            int c = 0;
            #pragma unroll
            for (int k = 0; k < CAP / 64; k++) c += ((kreg[k] >> 15) <= mid) ? 1 : 0;
            #pragma unroll
            for (int off = 32; off > 0; off >>= 1) c += __shfl_xor(c, off);
            if (c >= KNN) hi = mid; else lo = mid + 1;
        }
        const unsigned int tstar = lo;         // minimal trunc-key with count >= 100

        #pragma unroll
        for (int k = 0; k < CAP / 64; k++) {
            // HARDENED: padding sentinel can never pass, even if tstar saturates
            if (kreg[k] != 0xFFFFFFFFu && (kreg[k] >> 15) <= tstar) {
                int idx = (int)(kreg[k] & 0x7fffu);    // ORIGINAL key index
                float kx = k_pos[3*idx], ky = k_pos[3*idx+1], kz = k_pos[3*idx+2];
                double dqx = (double)qx[qw], dqy = (double)qy[qw], dqz = (double)qz[qw];
                double dkx = (double)kx, dky = (double)ky, dkz = (double)kz;
                double sq64 = dqx * dqx + dqy * dqy + dqz * dqz;
                double sk64 = dkx * dkx + dky * dky + dkz * dkz;
                double dot64 = dqx * dkx + dqy * dky + dqz * dkz;
                double d2 = sq64 + sk64 - 2.0 * dot64;
                if (d2 < 0.0) d2 = 0.0;
                unsigned long long kb = (unsigned long long)__double_as_longlong(d2);
                int pos = atomicAdd(&sCnt2[qw], 1);
                if (pos < RCAP)
                    refine[qw * RCAP + pos] = (kb & ~0x7fffULL) | (unsigned long long)idx;
            }
        }
    }
    __syncthreads();

    // ---- phase 6: register bitonic sort of 128 u64, DUPLICATED in both waves ----
    unsigned long long v0, v1;
    {
        const int cnt2 = min(sCnt2[qw], RCAP);
        v0 = (lane < cnt2)      ? refine[qw * RCAP + lane]      : ~0ULL;
        v1 = (64 + lane < cnt2) ? refine[qw * RCAP + 64 + lane] : ~0ULL;
    }
    #pragma unroll
    for (int k = 2; k <= 128; k <<= 1) {
        #pragma unroll
        for (int j = 64; j > 0; j >>= 1) {
            if (j > (k >> 1)) continue;
            if (j == 64) {  // cross-reg, same lane (only k=128); asc always
                unsigned long long mn = v0 < v1 ? v0 : v1;
                unsigned long long mx = v0 < v1 ? v1 : v0;
                v0 = mn; v1 = mx;
            } else {
                unsigned long long o0 = __shfl_xor(v0, j);
                unsigned long long o1 = __shfl_xor(v1, j);
                bool lower = (lane & j) == 0;
                bool asc0 = ((lane & k) == 0);          // element e0 = lane
                bool asc1 = (((64 + lane) & k) == 0);   // element e1 = 64+lane
                v0 = ((v0 < o0) == (lower == asc0)) ? v0 : o0;
                v1 = ((v1 < o1) == (lower == asc1)) ? v1 : o1;
            }
        }
    }
    const int id0r = (int)(v0 & 0x7fffULL);
    const int id1r = (int)(v1 & 0x7fffULL);

    // ---- phase 7: attention scores, row-split between the wave pair ----
    const int qn = qi[qw];
    const float4 qv = ((const float4*)(q_feat + (size_t)qn * C))[lane];
    {
        const int ibeg = role ? RSPLIT : 0;
        const int iend = role ? KNN : RSPLIT;
        for (int i = ibeg; i < iend; i += 4) {
            const int rsel = i >> 6, base = i & 63;
            const int idsrc = rsel ? id1r : id0r;
            int id0 = __shfl(idsrc, base + 0);
            int id1 = __shfl(idsrc, base + 1);
            int id2 = __shfl(idsrc, base + 2);
            int id3 = __shfl(idsrc, base + 3);
            float4 k0 = ((const float4*)(k_feat + (size_t)id0 * C))[lane];
            float4 k1 = ((const float4*)(k_feat + (size_t)id1 * C))[lane];
            float4 k2 = ((const float4*)(k_feat + (size_t)id2 * C))[lane];
            float4 k3 = ((const float4*)(k_feat + (size_t)id3 * C))[lane];
            float d0 = qv.x*k0.x + qv.y*k0.y + qv.z*k0.z + qv.w*k0.w;
            float d1 = qv.x*k1.x + qv.y*k1.y + qv.z*k1.z + qv.w*k1.w;
            float d2 = qv.x*k2.x + qv.y*k2.y + qv.z*k2.z + qv.w*k2.w;
            float d3 = qv.x*k3.x + qv.y*k3.y + qv.z*k3.z + qv.w*k3.w;
            #pragma unroll
            for (int off = 32; off > 0; off >>= 1) {
                d0 += __shfl_xor(d0, off);
                d1 += __shfl_xor(d1, off);
                d2 += __shfl_xor(d2, off);
                d3 += __shfl_xor(d3, off);
            }
            if (lane == 0) {
                sArr[qw * 128 + i + 0] = d0 * 0.0625f;
                sArr[qw * 128 + i + 1] = d1 * 0.0625f;
                sArr[qw * 128 + i + 2] = d2 * 0.0625f;
                sArr[qw * 128 + i + 3] = d3 * 0.0625f;
            }
        }
    }
    __syncthreads();

    // ---- phase 8: softmax over 100, DUPLICATED (deterministic) ----
    float invS, e0v, e1v;
    {
        float a = sArr[qw * 128 + lane];                       // rows 0-63
        bool hasB = (lane + 64 < KNN);
        float b = hasB ? sArr[qw * 128 + 64 + lane] : -3.0e38f;
        float mx = fmaxf(a, b);
        #pragma unroll
        for (int off = 32; off > 0; off >>= 1) mx = fmaxf(mx, __shfl_xor(mx, off));
        e0v = expf(a - mx);
        e1v = hasB ? expf(b - mx) : 0.0f;
        float s = e0v + e1v;
        #pragma unroll
        for (int off = 32; off > 0; off >>= 1) s += __shfl_xor(s, off);
        invS = 1.0f / s;
    }

    // ---- phase 9: PV gather, row-split ----
    float4 acc = make_float4(0.f, 0.f, 0.f, 0.f);
    {
        const int ibeg = role ? RSPLIT : 0;
        const int iend = role ? KNN : RSPLIT;
        for (int i = ibeg; i < iend; i += 4) {
            const int rsel = i >> 6, base = i & 63;
            const int idsrc = rsel ? id1r : id0r;
            const float esrc = rsel ? e1v : e0v;
            int id0 = __shfl(idsrc, base + 0);
            int id1 = __shfl(idsrc, base + 1);
            int id2 = __shfl(idsrc, base + 2);
            int id3 = __shfl(idsrc, base + 3);
            float w0 = __shfl(esrc, base + 0);
            float w1 = __shfl(esrc, base + 1);
            float w2 = __shfl(esrc, base + 2);
            float w3 = __shfl(esrc, base + 3);
            float4 p0 = ((const float4*)(v_feat + (size_t)id0 * C))[lane];
            float4 p1 = ((const float4*)(v_feat + (size_t)id1 * C))[lane];
            float4 p2 = ((const float4*)(v_feat + (size_t)id2 * C))[lane];
            float4 p3 = ((const float4*)(v_feat + (size_t)id3 * C))[lane];
            acc.x = fmaf(w0, p0.x, acc.x); acc.y = fmaf(w0, p0.y, acc.y);
            acc.z = fmaf(w0, p0.z, acc.z); acc.w = fmaf(w0, p0.w, acc.w);
            acc.x = fmaf(w1, p1.x, acc.x); acc.y = fmaf(w1, p1.y, acc.y);
            acc.z = fmaf(w1, p1.z, acc.z); acc.w = fmaf(w1, p1.w, acc.w);
            acc.x = fmaf(w2, p2.x, acc.x); acc.y = fmaf(w2, p2.y, acc.y);
            acc.z = fmaf(w2, p2.z, acc.z); acc.w = fmaf(w2, p2.w, acc.w);
            acc.x = fmaf(w3, p3.x, acc.x); acc.y = fmaf(w3, p3.y, acc.y);
            acc.z = fmaf(w3, p3.z, acc.z); acc.w = fmaf(w3, p3.w, acc.w);
        }
    }
    if (role == 1) accbuf[qw * 64 + lane] = acc;
    __syncthreads();

    // ---- phase 10: combine partials, LayerNorm, store (primary wave) ----
    if (role == 0) {
        float4 part = accbuf[qw * 64 + lane];
        acc.x += part.x; acc.y += part.y; acc.z += part.z; acc.w += part.w;
        // y = 2x (res_feat fully overwritten by the scatter -> res + x = 2x)
        float4 y;
        y.x = 2.0f * acc.x * invS; y.y = 2.0f * acc.y * invS;
        y.z = 2.0f * acc.z * invS; y.w = 2.0f * acc.w * invS;

        float t1 = y.x + y.y + y.z + y.w;
        float t2 = y.x*y.x + y.y*y.y + y.z*y.z + y.w*y.w;
        #pragma unroll
        for (int off = 32; off > 0; off >>= 1) {
            t1 += __shfl_xor(t1, off);
            t2 += __shfl_xor(t2, off);
        }
        float mean = t1 * (1.0f / C);
        float var  = fmaxf(t2 * (1.0f / C) - mean * mean, 0.0f);
        float rstd = 1.0f / sqrtf(var + 1e-5f);

        const float4 g4 = ((const float4*)gamma)[lane];
        const float4 b4 = ((const float4*)beta)[lane];
        float4 o;
        o.x = (y.x - mean) * rstd * g4.x + b4.x;
        o.y = (y.y - mean) * rstd * g4.y + b4.y;
        o.z = (y.z - mean) * rstd * g4.z + b4.z;
        o.w = (y.w - mean) * rstd * g4.w + b4.w;
        ((float4*)(out + (size_t)qn * C))[lane] = o;
    }
}

extern "C" void kernel_launch(void* const* d_in, const int* in_sizes, int n_in,
                              void* d_out, int out_size, void* d_ws, size_t ws_size,
                              hipStream_t stream) {
    // setup_inputs order: res_feat, q_feat, k_feat, v_feat, q_pos, k_pos, gamma, beta
    // res_feat (d_in[0]) is dead: scatter overwrites all rows, y = 2x.
    const float* q_feat = (const float*)d_in[1];
    const float* k_feat = (const float*)d_in[2];
    const float* v_feat = (const float*)d_in[3];
    const float* q_pos  = (const float*)d_in[4];
    const float* k_pos  = (const float*)d_in[5];
    const float* gamma  = (const float*)d_in[6];
    const float* beta   = (const float*)d_in[7];
    float* out = (float*)d_out;

    char* ws = (char*)d_ws;
    float4* kpkS    = (float4*)(ws + WS_KPKS);
    int* cellStart  = (int*)(ws + WS_CSTART);
    int* cellCur    = (int*)(ws + WS_CCNT);
    int* binCnt     = (int*)(ws + WS_BINCNT);
    int* binOf      = (int*)(ws + WS_BINOF);
    int* binOff     = (int*)(ws + WS_BINOFF);
    int* sortedIdx  = (int*)(ws + WS_SORTED);

    // zero cellCnt + binCnt in one contiguous memset
    hipMemsetAsync(cellCur, 0, (NCELL + 512) * sizeof(int), stream);
    count_all  <<<NKV / 256, 256, 0, stream>>>(k_pos, q_pos, cellCur, binOf, binCnt);
    cell_prefix<<<1, 1024, 0, stream>>>(cellCur, cellStart, cellCur, binCnt, binOff);
    scatter_all<<<NKV / 256, 256, 0, stream>>>(k_pos, cellCur, kpkS,
                                               binOf, binOff, sortedIdx);
    sparse_attn_fused<<<NQ / QB, 512, 0, stream>>>(q_feat, k_feat, v_feat,
                                                   q_pos, k_pos, kpkS, cellStart,
                                                   sortedIdx, gamma, beta, out);
}